// Round 8
// baseline (1209.369 us; speedup 1.0000x reference)
//
#include <hip/hip_runtime.h>
#include <cstdint>
#include <cstddef>

#define BB 16
#define PP 19248
#define NOBJ 32
#define NCLS 81
#define POS_TH 0.5f
#define NEG_TH 0.4f
#define VAR0 0.1f
#define VAR1 0.2f
#define NEGPOS 3

#define MTB 256
#define NMB ((PP + MTB - 1) / MTB)    // 76
#define MAINB 1024
#define ROWS_PB 128                    // rows per k_main block (8 rows/wave * 16 waves)
#define NSLOT ((PP + ROWS_PB - 1) / ROWS_PB)   // 151 blocks/batch
#define NSLOTW (NSLOT * 16)            // 2416 per-wave slots/batch

// object-parallel match parameters
#define MCH 8                          // prior chunks per object
#define CHLEN (PP / MCH)               // 2406 (exact)
#define MJOBS (BB * NOBJ * MCH)        // 4096 wave-jobs
#define MBLK (MJOBS / 4)               // 1024 blocks of 4 waves

// histogram select parameters
#define HSHIFT 19
#define HSIZE 8192                     // bins = bits >> 19 (13 bits)
#define HPT (HSIZE / MAINB)            // 8 bins per thread
#define CAP HSIZE                      // collection buffer reuses hist LDS

// workspace header layout (all zeroed by one memset)
#define OFF_GKEY 0                     // 16*32*8 = 4096
#define OFF_ACC 4096                   // 8
#define OFF_ACCNP 4104                 // 4
#define OFF_DONE 4108                  // 4
#define OFF_FCNT 4112                  // 16*32*4 = 2048 -> 6160
#define OFF_BCNT 6160                  // 16*4 = 64 -> 6224
#define OFF_BP 6272                    // BB*PP*4 = 1231872 -> 1238144
#define HDR_ZERO (OFF_BP + (size_t)BB * PP * 4)   // memset covers header + bp

// ---------------- match: per-gt best prior, object-parallel; 8th chunk-finisher patches bp ----------
__global__ __launch_bounds__(MTB) void k_match(const float* __restrict__ priors,
                                               const float* __restrict__ gt_boxes,
                                               const int* __restrict__ gt_labels,
                                               unsigned long long* __restrict__ gkey,
                                               unsigned* __restrict__ fcnt,
                                               unsigned* __restrict__ bp) {
    const int wid = threadIdx.x >> 6, lane = threadIdx.x & 63;
    const int job = blockIdx.x * 4 + wid;        // 0..4095
    const int b = job >> 8;                      // 256 jobs per batch
    const int n = (job >> 3) & 31;
    const int c = job & 7;

    const float4 g = ((const float4*)gt_boxes)[b * NOBJ + n];   // wave-uniform
    float garea;
    {
#pragma clang fp contract(off)
        garea = (g.z - g.x) * (g.w - g.y);
    }

    unsigned long long bestkey = 0ull;
    const int pbeg = c * CHLEN;
    const int pend = pbeg + CHLEN;
    for (int p = pbeg + lane; p < pend; p += 64) {
        float4 pr = ((const float4*)priors)[p];
        float iou;
        {
#pragma clang fp contract(off)
            float hw = pr.z / 2.0f, hh = pr.w / 2.0f;
            float px1 = pr.x - hw, py1 = pr.y - hh, px2 = pr.x + hw, py2 = pr.y + hh;
            float parea = (px2 - px1) * (py2 - py1);
            float ix1 = fmaxf(g.x, px1), iy1 = fmaxf(g.y, py1);
            float ix2 = fminf(g.z, px2), iy2 = fminf(g.w, py2);
            float iw = fmaxf(ix2 - ix1, 0.0f), ih = fmaxf(iy2 - iy1, 0.0f);
            float inter = iw * ih;
            iou = inter / (garea + parea - inter);
        }
        // key: larger iou wins; tie -> smaller p (first-max, matches jnp.argmax axis=1)
        unsigned long long key = (((unsigned long long)__float_as_uint(iou)) << 32) |
                                 (unsigned long long)(0xFFFFFFFFu - (unsigned)p);
        if (key > bestkey) bestkey = key;
    }
#pragma unroll
    for (int m = 1; m < 64; m <<= 1) {
        unsigned long long o = __shfl_xor(bestkey, m, 64);
        if (o > bestkey) bestkey = o;
    }
    if (lane == 0) {
        atomicMax(&gkey[b * NOBJ + n], bestkey);
        __threadfence();
        unsigned prev = atomicAdd(&fcnt[b * NOBJ + n], 1u);
        if (prev == MCH - 1) {
            // all 8 chunks applied their max: gkey final. Patch bp (bit31 beats any natural code;
            // atomicMax vs k_prior's atomicMax commutes, so launch order doesn't matter).
            unsigned long long key = atomicMax(&gkey[b * NOBJ + n], 0ull);   // atomic read (L2)
            unsigned pstar = 0xFFFFFFFFu - (unsigned)(key & 0xFFFFFFFFull);
            int lab = gt_labels[b * NOBJ + n];
            unsigned val = 0x80000000u | ((unsigned)n << 8) | (unsigned)(lab + 2);
            atomicMax(&bp[(size_t)b * PP + pstar], val);
        }
    }
}

// ---------------- prior: per-prior best gt -> packed (ti<<8 | conf_c+1) via atomicMax on zeroed bp ----
__global__ __launch_bounds__(MTB) void k_prior(const float* __restrict__ priors,
                                               const float* __restrict__ gt_boxes,
                                               const int* __restrict__ gt_labels,
                                               unsigned* __restrict__ bp) {
    const int b = blockIdx.y;
    const int p = blockIdx.x * MTB + threadIdx.x;
    __shared__ float4 sg[NOBJ];
    __shared__ int slab[NOBJ];
    if (threadIdx.x < NOBJ) {
        sg[threadIdx.x] = ((const float4*)gt_boxes)[b * NOBJ + threadIdx.x];
        slab[threadIdx.x] = gt_labels[b * NOBJ + threadIdx.x];
    }
    __syncthreads();
    if (p >= PP) return;

    float4 pr = ((const float4*)priors)[p];
    float px1, py1, px2, py2, parea;
    {
#pragma clang fp contract(off)
        float hw = pr.z / 2.0f, hh = pr.w / 2.0f;
        px1 = pr.x - hw; py1 = pr.y - hh; px2 = pr.x + hw; py2 = pr.y + hh;
        parea = (px2 - px1) * (py2 - py1);
    }

    float best = -1.0f;
    int bn = 0;
#pragma unroll 4
    for (int n = 0; n < NOBJ; ++n) {
        float4 g = sg[n];
        float iou;
        {
#pragma clang fp contract(off)
            float ix1 = fmaxf(g.x, px1), iy1 = fmaxf(g.y, py1);
            float ix2 = fminf(g.z, px2), iy2 = fminf(g.w, py2);
            float iw = fmaxf(ix2 - ix1, 0.0f), ih = fmaxf(iy2 - iy1, 0.0f);
            float inter = iw * ih;
            float garea = (g.z - g.x) * (g.w - g.y);
            iou = inter / (garea + parea - inter);
        }
        if (iou > best) { best = iou; bn = n; }   // strict > : first-max (argmax axis=0)
    }
    // cc = conf_c + 1: neutral->0, background->1, positive->lab+2  (bit31 clear: force always wins)
    unsigned cc;
    if (best < NEG_TH) cc = 1u;
    else if (best < POS_TH) cc = 0u;
    else cc = (unsigned)(slab[bn] + 2);
    atomicMax(&bp[(size_t)b * PP + p], ((unsigned)bn << 8) | cc);
}

__device__ __forceinline__ float sl1(float d) {
    float ad = fabsf(d);
    return ad < 1.0f ? 0.5f * d * d : ad - 0.5f;
}

// ---------------- main: R5 form + per-batch tail select by the last-arriving block ----------------
__global__ __launch_bounds__(MAINB) void k_main(const float* __restrict__ loc_data,
                                                const float* __restrict__ conf_data,
                                                const float* __restrict__ priors,
                                                const float* __restrict__ gt_boxes,
                                                const unsigned* __restrict__ bp,
                                                float* __restrict__ mine,
                                                float* __restrict__ p_ll,
                                                float* __restrict__ p_lc,
                                                int* __restrict__ p_np,
                                                unsigned* __restrict__ bcnt,
                                                float* __restrict__ acc,
                                                int* __restrict__ acc_np,
                                                unsigned* __restrict__ done,
                                                float* __restrict__ out) {
    const int b = blockIdx.y;
    const int t = threadIdx.x;
    const int wid = t >> 6;            // 0..15
    const int lane = t & 63;
    const int g = lane >> 3;           // row-group within wave: 0..7
    const int j = lane & 7;            // lane within row-group
    const int rbase = blockIdx.x * ROWS_PB + wid * 8;
    const int r = rbase + g;           // wave-uniform validity: PP % 8 == 0
    const bool valid = r < PP;
    const int slot = blockIdx.x * 16 + wid;

    // loads: 10 conf dwords (classes j, j+8, ..., j+72), c80 on j==0, packed match word
    const float* rowp = conf_data + ((size_t)b * PP + r) * NCLS;
    float c[10];
#pragma unroll
    for (int i = 0; i < 10; ++i) c[i] = 0.0f;
    float c80 = 0.0f;
    unsigned w = 1u;                   // background for invalid lanes (harmless)
    if (valid) {
#pragma unroll
        for (int i = 0; i < 10; ++i) c[i] = rowp[j + 8 * i];
        if (j == 0) c80 = rowp[80];
        w = bp[(size_t)b * PP + r];
    }

    // parallel logsumexp across the 8-lane group
    float s = 0.0f;
#pragma unroll
    for (int i = 0; i < 10; ++i) s += __expf(c[i]);
    if (j == 0) s += __expf(c80);
    s += __shfl_xor(s, 1, 64);
    s += __shfl_xor(s, 2, 64);
    s += __shfl_xor(s, 4, 64);
    const float lse = __logf(s);

    const int cc = (int)(w & 0xFFu);   // 0 neutral, 1 background, >=2 positive (lab+2)

    float my_ll = 0.0f, my_lc = 0.0f;
    int my_pos = 0;

    if (valid && j == 0) {
        // background nll uses this lane's own c[0] (= row[0]); no extra load
        mine[(size_t)b * PP + r] = (cc == 1) ? (lse - c[0]) : 0.0f;
        if (cc >= 2) {                 // rare branch: positives only
            my_pos = 1;
            my_lc = lse - rowp[cc - 1];
            const int ti = (int)((w >> 8) & 63u);
            float4 gbox = ((const float4*)gt_boxes)[b * NOBJ + ti];
            float4 pr = ((const float4*)priors)[r];
            float mcx = (gbox.x + gbox.z) / 2.0f, mcy = (gbox.y + gbox.w) / 2.0f;
            float mw = gbox.z - gbox.x, mh = gbox.w - gbox.y;
            float t0 = (mcx - pr.x) / (VAR0 * pr.z);
            float t1 = (mcy - pr.y) / (VAR0 * pr.w);
            float t2 = logf(mw / pr.z) / VAR1;
            float t3 = logf(mh / pr.w) / VAR1;
            float4 ld = ((const float4*)loc_data)[(size_t)b * PP + r];
            my_ll = sl1(ld.x - t0) + sl1(ld.y - t1) + sl1(ld.z - t2) + sl1(ld.w - t3);
        }
    }

    // per-wave slot store; skip the reduce when the wave has no positives (~99%)
    if (__ballot(my_pos != 0) == 0ull) {
        if (lane == 0) {
            p_ll[b * NSLOTW + slot] = 0.0f;
            p_lc[b * NSLOTW + slot] = 0.0f;
            p_np[b * NSLOTW + slot] = 0;
        }
    } else {
        for (int off = 32; off > 0; off >>= 1) {
            my_ll += __shfl_down(my_ll, off, 64);
            my_lc += __shfl_down(my_lc, off, 64);
            my_pos += __shfl_down(my_pos, off, 64);
        }
        if (lane == 0) {
            p_ll[b * NSLOTW + slot] = my_ll;
            p_lc[b * NSLOTW + slot] = my_lc;
            p_np[b * NSLOTW + slot] = my_pos;
        }
    }

    // ---- last block of this batch runs the select tail ----
    __shared__ unsigned s_isLast;
    __threadfence();                   // drain mine/p_* stores to L2 before the arrival tick
    if (t == 0) s_isLast = (atomicAdd(&bcnt[b], 1u) == (unsigned)(NSLOT - 1)) ? 1u : 0u;
    __syncthreads();
    if (s_isLast == 0u) return;
    __threadfence();                   // invalidate L1: see other blocks' mine/p_* stores

    // ======== select for batch b (proven R2-R6 algorithm, 1024 threads) ========
    const int tid = t;
    constexpr int NW = MAINB / 64;

    __shared__ unsigned hist[HSIZE];           // 32 KB; reused as collection buffer
    __shared__ unsigned s_tsum[MAINB];         // 4 KB
    __shared__ unsigned s_wsum[NW];
    __shared__ float rll[NW], rlc[NW];
    __shared__ int rnp[NW];
    __shared__ float rs1[NW], rs2[NW];
    __shared__ unsigned rc2[NW];
    __shared__ float s_ll, s_lc, s_neg;
    __shared__ int s_np, s_B, s_G1;
    __shared__ unsigned s_cntB, s_cnt, s_prefix;
    __shared__ int s_rem;
    __shared__ unsigned h16[16];
    __shared__ unsigned swh[NW * 16];
    __shared__ unsigned stot[16];

    // ---- 1. reduce this batch's partial slots ----
    float ll = 0.0f, lc = 0.0f;
    int np = 0;
    for (int i = tid; i < NSLOTW; i += MAINB) {
        ll += p_ll[b * NSLOTW + i];
        lc += p_lc[b * NSLOTW + i];
        np += p_np[b * NSLOTW + i];
    }
    for (int off = 32; off > 0; off >>= 1) {
        ll += __shfl_down(ll, off, 64);
        lc += __shfl_down(lc, off, 64);
        np += __shfl_down(np, off, 64);
    }
    if (lane == 0) { rll[wid] = ll; rlc[wid] = lc; rnp[wid] = np; }
    __syncthreads();
    if (tid == 0) {
        float a = 0.0f, cx = 0.0f;
        int n = 0;
        for (int w2 = 0; w2 < NW; ++w2) { a += rll[w2]; cx += rlc[w2]; n += rnp[w2]; }
        s_ll = a; s_lc = cx; s_np = n;
        s_neg = 0.0f;
    }
    __syncthreads();
    const int np_b = s_np;
    const int k = min(NEGPOS * np_b, PP - 1);

    const float* mv = mine + (size_t)b * PP;
    const float4* mv4 = (const float4*)mv;
    constexpr int PP4 = PP / 4;   // 4812

    if (k > 0) {
        // ---- 2. scan 1: 8192-bin LDS histogram of bits>>19 ----
        for (int i = tid; i < HSIZE; i += MAINB) hist[i] = 0u;
        __syncthreads();
        for (int i = tid; i < PP4; i += MAINB) {
            float4 v = mv4[i];
            atomicAdd(&hist[__float_as_uint(v.x) >> HSHIFT], 1u);
            atomicAdd(&hist[__float_as_uint(v.y) >> HSHIFT], 1u);
            atomicAdd(&hist[__float_as_uint(v.z) >> HSHIFT], 1u);
            atomicAdd(&hist[__float_as_uint(v.w) >> HSHIFT], 1u);
        }
        __syncthreads();

        // ---- 3. find boundary bin B (suffix scan from top: waves -> threads -> bins) ----
        unsigned tsum = 0;
        const int hb = tid * HPT;
#pragma unroll
        for (int v = 0; v < HPT; ++v) tsum += hist[hb + v];
        s_tsum[tid] = tsum;
        unsigned wsum = tsum;
        for (int off = 32; off > 0; off >>= 1) wsum += __shfl_down(wsum, off, 64);
        if (lane == 0) s_wsum[wid] = wsum;
        __syncthreads();
        if (tid == 0) {
            unsigned cum = 0;
            int w2 = NW - 1;
            for (; w2 > 0; --w2) {
                if (cum + s_wsum[w2] >= (unsigned)k) break;
                cum += s_wsum[w2];
            }
            int tt = (w2 + 1) * 64 - 1;
            for (; tt > w2 * 64; --tt) {
                if (cum + s_tsum[tt] >= (unsigned)k) break;
                cum += s_tsum[tt];
            }
            int bin = tt * HPT + HPT - 1;
            for (; bin > tt * HPT; --bin) {
                if (cum + hist[bin] >= (unsigned)k) break;
                cum += hist[bin];
            }
            s_B = bin;
            s_G1 = (int)cum;          // count strictly above bin B
            s_cntB = hist[bin];
            s_cnt = 0u;
        }
        __syncthreads();
        const int B = s_B;
        const int r2 = k - s_G1;                        // 1 <= r2 <= cntB
        const unsigned cntB = s_cntB;
        const unsigned bin_lo = (unsigned)B << HSHIFT;
        const unsigned hi_base = (unsigned)(B + 1) << HSHIFT;
        unsigned* cbuf = hist;                          // reuse (all hist reads are done)

        if (cntB <= CAP) {
            // ---- 4. scan 2: exact sum above bin B + collect bin-B elements into LDS ----
            float S1 = 0.0f;
            for (int i = tid; i < PP4; i += MAINB) {
                float4 v = mv4[i];
                unsigned bx = __float_as_uint(v.x);
                unsigned by = __float_as_uint(v.y);
                unsigned bz = __float_as_uint(v.z);
                unsigned bw = __float_as_uint(v.w);
                if (bx >= hi_base) S1 += v.x;
                else if (bx >= bin_lo) cbuf[atomicAdd(&s_cnt, 1u)] = bx;
                if (by >= hi_base) S1 += v.y;
                else if (by >= bin_lo) cbuf[atomicAdd(&s_cnt, 1u)] = by;
                if (bz >= hi_base) S1 += v.z;
                else if (bz >= bin_lo) cbuf[atomicAdd(&s_cnt, 1u)] = bz;
                if (bw >= hi_base) S1 += v.w;
                else if (bw >= bin_lo) cbuf[atomicAdd(&s_cnt, 1u)] = bw;
            }
            for (int off = 32; off > 0; off >>= 1) S1 += __shfl_down(S1, off, 64);
            if (lane == 0) rs1[wid] = S1;
            __syncthreads();   // also fences the collection writes

            // ---- 5. refine low 19 bits among the cntB collected elements (LDS-resident) ----
            if (tid == 0) { s_prefix = bin_lo; s_rem = r2; }
            __syncthreads();
            for (int pass = 0; pass < 5; ++pass) {
                const int shift = (pass < 4) ? (15 - 4 * pass) : 0;
                const int width = (pass < 4) ? 4 : 3;
                const int nb = 1 << width;
                const unsigned hm = 0xFFFFFFFFu << (shift + width);
                if (tid < 16) h16[tid] = 0u;
                __syncthreads();
                const unsigned prefix = s_prefix;
                for (unsigned i = tid; i < cntB; i += MAINB) {
                    unsigned bits = cbuf[i];
                    if ((bits & hm) == prefix)
                        atomicAdd(&h16[(bits >> shift) & (nb - 1)], 1u);
                }
                __syncthreads();
                if (tid == 0) {
                    int rem = s_rem;
                    unsigned cum = 0;
                    int chosen = 0;
                    for (int v = nb - 1; v >= 0; --v) {
                        unsigned cv = h16[v];
                        if (cum + cv >= (unsigned)rem) { chosen = v; s_rem = rem - (int)cum; break; }
                        cum += cv;
                    }
                    s_prefix = prefix | ((unsigned)chosen << shift);
                }
                __syncthreads();
            }
            const unsigned T = s_prefix;   // exact bits of the r2-th largest within bin B

            // ---- 6. final: sum collected > T, tie-fill with T ----
            float S2 = 0.0f;
            unsigned c2 = 0;
            for (unsigned i = tid; i < cntB; i += MAINB) {
                unsigned bits = cbuf[i];
                if (bits > T) { S2 += __uint_as_float(bits); c2++; }
            }
            for (int off = 32; off > 0; off >>= 1) {
                S2 += __shfl_down(S2, off, 64);
                c2 += __shfl_down(c2, off, 64);
            }
            if (lane == 0) { rs2[wid] = S2; rc2[wid] = c2; }
            __syncthreads();
            if (tid == 0) {
                float S1t = 0.0f, S2t = 0.0f;
                unsigned c2t = 0;
                for (int w2 = 0; w2 < NW; ++w2) { S1t += rs1[w2]; S2t += rs2[w2]; c2t += rc2[w2]; }
                s_neg = S1t + S2t + (float)(r2 - (int)c2t) * __uint_as_float(T);
            }
            __syncthreads();
        } else {
            // ---- fallback (collection overflow — practically unreachable): 8-pass global radix ----
            if (tid == 0) { s_prefix = 0u; s_rem = k; }
            __syncthreads();
            for (int pass = 0; pass < 8; ++pass) {
                const int shift = 28 - 4 * pass;
                const unsigned hm = (pass == 0) ? 0u : (0xFFFFFFFFu << (shift + 4));
                const unsigned prefix = s_prefix;
                unsigned cnt[16];
#pragma unroll
                for (int v = 0; v < 16; ++v) cnt[v] = 0u;
                for (int i = tid; i < PP; i += MAINB) {
                    unsigned bits = __float_as_uint(mv[i]);
                    unsigned key = ((bits & hm) == prefix) ? ((bits >> shift) & 15u) : 16u;
                    if (__any(key != 16u)) {
#pragma unroll
                        for (int v = 0; v < 16; ++v)
                            cnt[v] += (unsigned)__popcll(__ballot(key == (unsigned)v));
                    }
                }
                if (lane == 0) {
#pragma unroll
                    for (int v = 0; v < 16; ++v) swh[wid * 16 + v] = cnt[v];
                }
                __syncthreads();
                if (tid < 16) {
                    unsigned tt = 0;
#pragma unroll
                    for (int w2 = 0; w2 < NW; ++w2) tt += swh[w2 * 16 + tid];
                    stot[tid] = tt;
                }
                __syncthreads();
                if (tid == 0) {
                    int rem = s_rem;
                    unsigned cum = 0;
                    int chosen = 0;
                    for (int v = 15; v >= 0; --v) {
                        unsigned cv = stot[v];
                        if (cum + cv >= (unsigned)rem) { chosen = v; s_rem = rem - (int)cum; break; }
                        cum += cv;
                    }
                    s_prefix = prefix | ((unsigned)chosen << shift);
                }
                __syncthreads();
            }
            const unsigned T = s_prefix;
            float sum = 0.0f;
            unsigned cnt = 0;
            for (int i = tid; i < PP; i += MAINB) {
                float v = mv[i];
                if (__float_as_uint(v) > T) { sum += v; cnt++; }
            }
            for (int off = 32; off > 0; off >>= 1) {
                sum += __shfl_down(sum, off, 64);
                cnt += __shfl_down(cnt, off, 64);
            }
            if (lane == 0) { rs2[wid] = sum; rc2[wid] = cnt; }
            __syncthreads();
            if (tid == 0) {
                float S = 0.0f;
                int G = 0;
                for (int w2 = 0; w2 < NW; ++w2) { S += rs2[w2]; G += (int)rc2[w2]; }
                s_neg = S + (float)(k - G) * __uint_as_float(T);
            }
            __syncthreads();
        }
    }

    if (tid == 0) {
        atomicAdd(&acc[0], s_ll);
        atomicAdd(&acc[1], s_lc + s_neg);
        atomicAdd(acc_np, np_b);
        __threadfence();
        unsigned prev = atomicAdd(done, 1u);
        if (prev == BB - 1) {
            int tp = atomicAdd(acc_np, 0);
            float N = (float)max(tp, 1);
            float a0 = atomicAdd(&acc[0], 0.0f);
            float a1 = atomicAdd(&acc[1], 0.0f);
            out[0] = a0 / N;
            out[1] = a1 / N;
        }
    }
}

extern "C" void kernel_launch(void* const* d_in, const int* in_sizes, int n_in,
                              void* d_out, int out_size, void* d_ws, size_t ws_size,
                              hipStream_t stream) {
    const float* loc    = (const float*)d_in[0];
    const float* conf   = (const float*)d_in[1];
    const float* priors = (const float*)d_in[2];
    const float* gt     = (const float*)d_in[3];
    const int*   labels = (const int*)d_in[4];
    float* out = (float*)d_out;

    char* ws = (char*)d_ws;
    const size_t SZ_BP = (size_t)BB * PP * 4;          // 1,231,872 B
    const size_t SZ_SLOT = (size_t)BB * NSLOTW * 4;    // 154,624 B
    unsigned long long* gkey = (unsigned long long*)(ws + OFF_GKEY);
    float*    acc    = (float*)   (ws + OFF_ACC);
    int*      acc_np = (int*)     (ws + OFF_ACCNP);
    unsigned* done   = (unsigned*)(ws + OFF_DONE);
    unsigned* fcnt   = (unsigned*)(ws + OFF_FCNT);
    unsigned* bcnt   = (unsigned*)(ws + OFF_BCNT);
    unsigned* bp     = (unsigned*)(ws + OFF_BP);
    float* mine = (float*)(ws + OFF_BP + SZ_BP);
    float* p_ll = (float*)(ws + OFF_BP + 2 * SZ_BP);
    float* p_lc = (float*)(ws + OFF_BP + 2 * SZ_BP + SZ_SLOT);
    int*   p_np = (int*)  (ws + OFF_BP + 2 * SZ_BP + 2 * SZ_SLOT);

    // zero header (gkey/acc/acc_np/done/fcnt/bcnt) + bp (needed for atomicMax correctness)
    (void)hipMemsetAsync(ws, 0, HDR_ZERO, stream);

    k_match<<<MBLK, MTB, 0, stream>>>(priors, gt, labels, gkey, fcnt, bp);

    dim3 pg(NMB, BB);
    k_prior<<<pg, MTB, 0, stream>>>(priors, gt, labels, bp);

    dim3 kg(NSLOT, BB);
    k_main<<<kg, MAINB, 0, stream>>>(loc, conf, priors, gt, bp,
                                     mine, p_ll, p_lc, p_np,
                                     bcnt, acc, acc_np, done, out);
}

// Round 9
// 210.619 us; speedup vs baseline: 5.7420x; 5.7420x over previous
//
#include <hip/hip_runtime.h>
#include <cstdint>
#include <cstddef>

#define BB 16
#define PP 19248
#define NOBJ 32
#define NCLS 81
#define POS_TH 0.5f
#define NEG_TH 0.4f
#define VAR0 0.1f
#define VAR1 0.2f
#define NEGPOS 3

#define MTB 256
#define NMB ((PP + MTB - 1) / MTB)    // 76
#define MAINB 1024
#define ROWS_PB 128                    // rows per k_main block (8 rows/wave * 16 waves)
#define NSLOT ((PP + ROWS_PB - 1) / ROWS_PB)   // 151 blocks/batch
#define NSLOTW (NSLOT * 16)            // 2416 per-wave slots/batch
#define ST 1024

// object-parallel match parameters
#define MCH 8                          // prior chunks per object
#define CHLEN (PP / MCH)               // 2406 (exact)
#define MJOBS (BB * NOBJ * MCH)        // 4096 wave-jobs
#define MBLK (MJOBS / 4)               // 1024 blocks of 4 waves

// histogram select parameters
#define HSHIFT 19
#define HSIZE 8192                     // bins = bits >> 19 (13 bits)
#define HPT (HSIZE / ST)               // 8 bins per thread
#define CAP HSIZE                      // collection buffer reuses hist LDS

// ---------------- match: per-gt best prior, object-parallel (1 wave = 1 (b,obj,chunk)) ----------------
__global__ __launch_bounds__(MTB) void k_match(const float* __restrict__ priors,
                                               const float* __restrict__ gt_boxes,
                                               unsigned long long* __restrict__ gkey) {
    const int wid = threadIdx.x >> 6, lane = threadIdx.x & 63;
    const int job = blockIdx.x * 4 + wid;        // 0..4095
    const int b = job >> 8;                      // 256 jobs per batch
    const int n = (job >> 3) & 31;
    const int c = job & 7;

    const float4 g = ((const float4*)gt_boxes)[b * NOBJ + n];   // wave-uniform
    float garea;
    {
#pragma clang fp contract(off)
        garea = (g.z - g.x) * (g.w - g.y);
    }

    unsigned long long bestkey = 0ull;
    const int pbeg = c * CHLEN;
    const int pend = pbeg + CHLEN;
    for (int p = pbeg + lane; p < pend; p += 64) {
        float4 pr = ((const float4*)priors)[p];
        float iou;
        {
#pragma clang fp contract(off)
            float hw = pr.z / 2.0f, hh = pr.w / 2.0f;
            float px1 = pr.x - hw, py1 = pr.y - hh, px2 = pr.x + hw, py2 = pr.y + hh;
            float parea = (px2 - px1) * (py2 - py1);
            float ix1 = fmaxf(g.x, px1), iy1 = fmaxf(g.y, py1);
            float ix2 = fminf(g.z, px2), iy2 = fminf(g.w, py2);
            float iw = fmaxf(ix2 - ix1, 0.0f), ih = fmaxf(iy2 - iy1, 0.0f);
            float inter = iw * ih;
            iou = inter / (garea + parea - inter);
        }
        // key: larger iou wins; tie -> smaller p (first-max, matches jnp.argmax axis=1)
        unsigned long long key = (((unsigned long long)__float_as_uint(iou)) << 32) |
                                 (unsigned long long)(0xFFFFFFFFu - (unsigned)p);
        if (key > bestkey) bestkey = key;
    }
#pragma unroll
    for (int m = 1; m < 64; m <<= 1) {
        unsigned long long o = __shfl_xor(bestkey, m, 64);
        if (o > bestkey) bestkey = o;
    }
    if (lane == 0) atomicMax(&gkey[b * NOBJ + n], bestkey);
}

// ---------------- prior: per-prior best gt -> packed (ti<<8 | conf_c+1), labels folded in ----------------
__global__ __launch_bounds__(MTB) void k_prior(const float* __restrict__ priors,
                                               const float* __restrict__ gt_boxes,
                                               const int* __restrict__ gt_labels,
                                               unsigned* __restrict__ bp) {
    const int b = blockIdx.y;
    const int p = blockIdx.x * MTB + threadIdx.x;
    __shared__ float4 sg[NOBJ];
    __shared__ int slab[NOBJ];
    if (threadIdx.x < NOBJ) {
        sg[threadIdx.x] = ((const float4*)gt_boxes)[b * NOBJ + threadIdx.x];
        slab[threadIdx.x] = gt_labels[b * NOBJ + threadIdx.x];
    }
    __syncthreads();
    if (p >= PP) return;

    float4 pr = ((const float4*)priors)[p];
    float px1, py1, px2, py2, parea;
    {
#pragma clang fp contract(off)
        float hw = pr.z / 2.0f, hh = pr.w / 2.0f;
        px1 = pr.x - hw; py1 = pr.y - hh; px2 = pr.x + hw; py2 = pr.y + hh;
        parea = (px2 - px1) * (py2 - py1);
    }

    float best = -1.0f;
    int bn = 0;
#pragma unroll 4
    for (int n = 0; n < NOBJ; ++n) {
        float4 g = sg[n];
        float iou;
        {
#pragma clang fp contract(off)
            float ix1 = fmaxf(g.x, px1), iy1 = fmaxf(g.y, py1);
            float ix2 = fminf(g.z, px2), iy2 = fminf(g.w, py2);
            float iw = fmaxf(ix2 - ix1, 0.0f), ih = fmaxf(iy2 - iy1, 0.0f);
            float inter = iw * ih;
            float garea = (g.z - g.x) * (g.w - g.y);
            iou = inter / (garea + parea - inter);
        }
        if (iou > best) { best = iou; bn = n; }   // strict > : first-max (argmax axis=0)
    }
    // cc = conf_c + 1: neutral->0, background->1, positive->lab+2
    unsigned cc;
    if (best < NEG_TH) cc = 1u;
    else if (best < POS_TH) cc = 0u;
    else cc = (unsigned)(slab[bn] + 2);
    bp[(size_t)b * PP + p] = ((unsigned)bn << 8) | cc;
}

// ---------------- force: patch the <=512 forced rows; bit31 wins, higher n = last-wins ----------------
__global__ __launch_bounds__(512) void k_force(const int* __restrict__ gt_labels,
                                               const unsigned long long* __restrict__ gkey,
                                               unsigned* __restrict__ bp) {
    const int i = threadIdx.x;          // 0..511
    const int b = i >> 5, n = i & 31;
    unsigned long long key = gkey[b * NOBJ + n];
    unsigned pstar = 0xFFFFFFFFu - (unsigned)(key & 0xFFFFFFFFull);
    int lab = gt_labels[b * NOBJ + n];
    unsigned val = 0x80000000u | ((unsigned)n << 8) | (unsigned)(lab + 2);
    atomicMax(&bp[(size_t)b * PP + pstar], val);
}

__device__ __forceinline__ float sl1(float d) {
    float ad = fabsf(d);
    return ad < 1.0f ? 0.5f * d * d : ad - 0.5f;
}

// ---------------- main: 8-lane LSE, 8 rows/wave; zero metadata work, per-wave slots ----------------
// wave = 8 rows (8 lanes each); block = 16 waves = 128 rows; NO __syncthreads, NO LDS.
__global__ __launch_bounds__(MAINB) void k_main(const float* __restrict__ loc_data,
                                                const float* __restrict__ conf_data,
                                                const float* __restrict__ priors,
                                                const float* __restrict__ gt_boxes,
                                                const unsigned* __restrict__ bp,
                                                float* __restrict__ mine,
                                                float* __restrict__ p_ll,
                                                float* __restrict__ p_lc,
                                                int* __restrict__ p_np) {
    const int b = blockIdx.y;
    const int t = threadIdx.x;
    const int wid = t >> 6;            // 0..15
    const int lane = t & 63;
    const int g = lane >> 3;           // row-group within wave: 0..7
    const int j = lane & 7;            // lane within row-group
    const int rbase = blockIdx.x * ROWS_PB + wid * 8;
    const int r = rbase + g;           // wave-uniform validity: PP % 8 == 0
    const bool valid = r < PP;
    const int slot = blockIdx.x * 16 + wid;

    // loads: 10 conf dwords (classes j, j+8, ..., j+72), c80 on j==0, packed match word
    const float* rowp = conf_data + ((size_t)b * PP + r) * NCLS;
    float c[10];
#pragma unroll
    for (int i = 0; i < 10; ++i) c[i] = 0.0f;
    float c80 = 0.0f;
    unsigned w = 1u;                   // background for invalid lanes (harmless)
    if (valid) {
#pragma unroll
        for (int i = 0; i < 10; ++i) c[i] = rowp[j + 8 * i];
        if (j == 0) c80 = rowp[80];
        w = bp[(size_t)b * PP + r];
    }

    // parallel logsumexp across the 8-lane group
    float s = 0.0f;
#pragma unroll
    for (int i = 0; i < 10; ++i) s += __expf(c[i]);
    if (j == 0) s += __expf(c80);
    s += __shfl_xor(s, 1, 64);
    s += __shfl_xor(s, 2, 64);
    s += __shfl_xor(s, 4, 64);
    const float lse = __logf(s);

    const int cc = (int)(w & 0xFFu);   // 0 neutral, 1 background, >=2 positive (lab+2)

    float my_ll = 0.0f, my_lc = 0.0f;
    int my_pos = 0;

    if (valid && j == 0) {
        // background nll uses this lane's own c[0] (= row[0]); no extra load
        mine[(size_t)b * PP + r] = (cc == 1) ? (lse - c[0]) : 0.0f;
        if (cc >= 2) {                 // rare branch: positives only
            my_pos = 1;
            my_lc = lse - rowp[cc - 1];
            const int ti = (int)((w >> 8) & 63u);
            float4 gbox = ((const float4*)gt_boxes)[b * NOBJ + ti];
            float4 pr = ((const float4*)priors)[r];
            float mcx = (gbox.x + gbox.z) / 2.0f, mcy = (gbox.y + gbox.w) / 2.0f;
            float mw = gbox.z - gbox.x, mh = gbox.w - gbox.y;
            float t0 = (mcx - pr.x) / (VAR0 * pr.z);
            float t1 = (mcy - pr.y) / (VAR0 * pr.w);
            float t2 = logf(mw / pr.z) / VAR1;
            float t3 = logf(mh / pr.w) / VAR1;
            float4 ld = ((const float4*)loc_data)[(size_t)b * PP + r];
            my_ll = sl1(ld.x - t0) + sl1(ld.y - t1) + sl1(ld.z - t2) + sl1(ld.w - t3);
        }
    }

    // per-wave slot store; skip the reduce when the wave has no positives (~99%)
    if (__ballot(my_pos != 0) == 0ull) {
        if (lane == 0) {
            p_ll[b * NSLOTW + slot] = 0.0f;
            p_lc[b * NSLOTW + slot] = 0.0f;
            p_np[b * NSLOTW + slot] = 0;
        }
    } else {
        for (int off = 32; off > 0; off >>= 1) {
            my_ll += __shfl_down(my_ll, off, 64);
            my_lc += __shfl_down(my_lc, off, 64);
            my_pos += __shfl_down(my_pos, off, 64);
        }
        if (lane == 0) {
            p_ll[b * NSLOTW + slot] = my_ll;
            p_lc[b * NSLOTW + slot] = my_lc;
            p_np[b * NSLOTW + slot] = my_pos;
        }
    }
}

// ---------------- select: histogram top-k (2 global scans) + LDS refine + fused finalize ----------------
__global__ __launch_bounds__(ST) void k_select(const float* __restrict__ mine,
                                               const float* __restrict__ p_ll,
                                               const float* __restrict__ p_lc,
                                               const int* __restrict__ p_np,
                                               float* __restrict__ acc,
                                               int* __restrict__ acc_np,
                                               unsigned* __restrict__ done,
                                               float* __restrict__ out) {
    const int b = blockIdx.x;
    const int tid = threadIdx.x;
    const int wid = tid >> 6, lane = tid & 63;
    constexpr int NW = ST / 64;

    __shared__ unsigned hist[HSIZE];           // 32 KB; reused as collection buffer
    __shared__ unsigned s_tsum[ST];            // 4 KB
    __shared__ unsigned s_wsum[NW];
    __shared__ float rll[NW], rlc[NW];
    __shared__ int rnp[NW];
    __shared__ float rs1[NW], rs2[NW];
    __shared__ unsigned rc2[NW];
    __shared__ float s_ll, s_lc, s_neg;
    __shared__ int s_np, s_B, s_G1;
    __shared__ unsigned s_cntB, s_cnt, s_prefix;
    __shared__ int s_rem;
    __shared__ unsigned h16[16];
    // fallback radix shared state
    __shared__ unsigned swh[NW * 16];
    __shared__ unsigned stot[16];

    // ---- 1. reduce this batch's partial slots ----
    float ll = 0.0f, lc = 0.0f;
    int np = 0;
    for (int i = tid; i < NSLOTW; i += ST) {
        ll += p_ll[b * NSLOTW + i];
        lc += p_lc[b * NSLOTW + i];
        np += p_np[b * NSLOTW + i];
    }
    for (int off = 32; off > 0; off >>= 1) {
        ll += __shfl_down(ll, off, 64);
        lc += __shfl_down(lc, off, 64);
        np += __shfl_down(np, off, 64);
    }
    if (lane == 0) { rll[wid] = ll; rlc[wid] = lc; rnp[wid] = np; }
    __syncthreads();
    if (tid == 0) {
        float a = 0.0f, c = 0.0f;
        int n = 0;
        for (int w = 0; w < NW; ++w) { a += rll[w]; c += rlc[w]; n += rnp[w]; }
        s_ll = a; s_lc = c; s_np = n;
        s_neg = 0.0f;
    }
    __syncthreads();
    const int np_b = s_np;
    const int k = min(NEGPOS * np_b, PP - 1);

    const float* mv = mine + (size_t)b * PP;
    const float4* mv4 = (const float4*)mv;
    constexpr int PP4 = PP / 4;   // 4812

    if (k > 0) {
        // ---- 2. scan 1: 8192-bin LDS histogram of bits>>19 (float4 loads, pipelined) ----
        for (int i = tid; i < HSIZE; i += ST) hist[i] = 0u;
        __syncthreads();
        for (int i = tid; i < PP4; i += ST) {
            float4 v = mv4[i];
            atomicAdd(&hist[__float_as_uint(v.x) >> HSHIFT], 1u);
            atomicAdd(&hist[__float_as_uint(v.y) >> HSHIFT], 1u);
            atomicAdd(&hist[__float_as_uint(v.z) >> HSHIFT], 1u);
            atomicAdd(&hist[__float_as_uint(v.w) >> HSHIFT], 1u);
        }
        __syncthreads();

        // ---- 3. find boundary bin B (suffix scan from top: waves -> threads -> bins) ----
        unsigned tsum = 0;
        const int hb = tid * HPT;
#pragma unroll
        for (int v = 0; v < HPT; ++v) tsum += hist[hb + v];
        s_tsum[tid] = tsum;
        unsigned wsum = tsum;
        for (int off = 32; off > 0; off >>= 1) wsum += __shfl_down(wsum, off, 64);
        if (lane == 0) s_wsum[wid] = wsum;
        __syncthreads();
        if (tid == 0) {
            unsigned cum = 0;
            int w = NW - 1;
            for (; w > 0; --w) {
                if (cum + s_wsum[w] >= (unsigned)k) break;
                cum += s_wsum[w];
            }
            int t = (w + 1) * 64 - 1;
            for (; t > w * 64; --t) {
                if (cum + s_tsum[t] >= (unsigned)k) break;
                cum += s_tsum[t];
            }
            int bin = t * HPT + HPT - 1;
            for (; bin > t * HPT; --bin) {
                if (cum + hist[bin] >= (unsigned)k) break;
                cum += hist[bin];
            }
            s_B = bin;
            s_G1 = (int)cum;          // count strictly above bin B
            s_cntB = hist[bin];
            s_cnt = 0u;
        }
        __syncthreads();
        const int B = s_B;
        const int r = k - s_G1;                         // 1 <= r <= cntB
        const unsigned cntB = s_cntB;
        const unsigned bin_lo = (unsigned)B << HSHIFT;
        const unsigned hi_base = (unsigned)(B + 1) << HSHIFT;
        unsigned* cbuf = hist;                          // reuse (all hist reads are done)

        if (cntB <= CAP) {
            // ---- 4. scan 2: exact sum above bin B + collect bin-B elements into LDS ----
            float S1 = 0.0f;
            for (int i = tid; i < PP4; i += ST) {
                float4 v = mv4[i];
                unsigned bx = __float_as_uint(v.x);
                unsigned by = __float_as_uint(v.y);
                unsigned bz = __float_as_uint(v.z);
                unsigned bw = __float_as_uint(v.w);
                if (bx >= hi_base) S1 += v.x;
                else if (bx >= bin_lo) cbuf[atomicAdd(&s_cnt, 1u)] = bx;
                if (by >= hi_base) S1 += v.y;
                else if (by >= bin_lo) cbuf[atomicAdd(&s_cnt, 1u)] = by;
                if (bz >= hi_base) S1 += v.z;
                else if (bz >= bin_lo) cbuf[atomicAdd(&s_cnt, 1u)] = bz;
                if (bw >= hi_base) S1 += v.w;
                else if (bw >= bin_lo) cbuf[atomicAdd(&s_cnt, 1u)] = bw;
            }
            for (int off = 32; off > 0; off >>= 1) S1 += __shfl_down(S1, off, 64);
            if (lane == 0) rs1[wid] = S1;
            __syncthreads();   // also fences the collection writes

            // ---- 5. refine low 19 bits among the cntB collected elements (LDS-resident) ----
            if (tid == 0) { s_prefix = bin_lo; s_rem = r; }
            __syncthreads();
            for (int pass = 0; pass < 5; ++pass) {
                const int shift = (pass < 4) ? (15 - 4 * pass) : 0;
                const int width = (pass < 4) ? 4 : 3;
                const int nb = 1 << width;
                const unsigned hm = 0xFFFFFFFFu << (shift + width);
                if (tid < 16) h16[tid] = 0u;
                __syncthreads();
                const unsigned prefix = s_prefix;
                for (unsigned i = tid; i < cntB; i += ST) {
                    unsigned bits = cbuf[i];
                    if ((bits & hm) == prefix)
                        atomicAdd(&h16[(bits >> shift) & (nb - 1)], 1u);
                }
                __syncthreads();
                if (tid == 0) {
                    int rem = s_rem;
                    unsigned cum = 0;
                    int chosen = 0;
                    for (int v = nb - 1; v >= 0; --v) {
                        unsigned c = h16[v];
                        if (cum + c >= (unsigned)rem) { chosen = v; s_rem = rem - (int)cum; break; }
                        cum += c;
                    }
                    s_prefix = prefix | ((unsigned)chosen << shift);
                }
                __syncthreads();
            }
            const unsigned T = s_prefix;   // exact bits of the r-th largest within bin B

            // ---- 6. final: sum collected > T, tie-fill with T ----
            float S2 = 0.0f;
            unsigned c2 = 0;
            for (unsigned i = tid; i < cntB; i += ST) {
                unsigned bits = cbuf[i];
                if (bits > T) { S2 += __uint_as_float(bits); c2++; }
            }
            for (int off = 32; off > 0; off >>= 1) {
                S2 += __shfl_down(S2, off, 64);
                c2 += __shfl_down(c2, off, 64);
            }
            if (lane == 0) { rs2[wid] = S2; rc2[wid] = c2; }
            __syncthreads();
            if (tid == 0) {
                float S1t = 0.0f, S2t = 0.0f;
                unsigned c2t = 0;
                for (int w = 0; w < NW; ++w) { S1t += rs1[w]; S2t += rs2[w]; c2t += rc2[w]; }
                s_neg = S1t + S2t + (float)(r - (int)c2t) * __uint_as_float(T);
            }
            __syncthreads();
        } else {
            // ---- fallback (collection overflow — practically unreachable): 8-pass global radix ----
            if (tid == 0) { s_prefix = 0u; s_rem = k; }
            __syncthreads();
            for (int pass = 0; pass < 8; ++pass) {
                const int shift = 28 - 4 * pass;
                const unsigned hm = (pass == 0) ? 0u : (0xFFFFFFFFu << (shift + 4));
                const unsigned prefix = s_prefix;
                unsigned cnt[16];
#pragma unroll
                for (int v = 0; v < 16; ++v) cnt[v] = 0u;
                for (int i = tid; i < PP; i += ST) {
                    unsigned bits = __float_as_uint(mv[i]);
                    unsigned key = ((bits & hm) == prefix) ? ((bits >> shift) & 15u) : 16u;
                    if (__any(key != 16u)) {
#pragma unroll
                        for (int v = 0; v < 16; ++v)
                            cnt[v] += (unsigned)__popcll(__ballot(key == (unsigned)v));
                    }
                }
                if (lane == 0) {
#pragma unroll
                    for (int v = 0; v < 16; ++v) swh[wid * 16 + v] = cnt[v];
                }
                __syncthreads();
                if (tid < 16) {
                    unsigned tt = 0;
#pragma unroll
                    for (int w = 0; w < NW; ++w) tt += swh[w * 16 + tid];
                    stot[tid] = tt;
                }
                __syncthreads();
                if (tid == 0) {
                    int rem = s_rem;
                    unsigned cum = 0;
                    int chosen = 0;
                    for (int v = 15; v >= 0; --v) {
                        unsigned c = stot[v];
                        if (cum + c >= (unsigned)rem) { chosen = v; s_rem = rem - (int)cum; break; }
                        cum += c;
                    }
                    s_prefix = prefix | ((unsigned)chosen << shift);
                }
                __syncthreads();
            }
            const unsigned T = s_prefix;
            float sum = 0.0f;
            unsigned cnt = 0;
            for (int i = tid; i < PP; i += ST) {
                float v = mv[i];
                if (__float_as_uint(v) > T) { sum += v; cnt++; }
            }
            for (int off = 32; off > 0; off >>= 1) {
                sum += __shfl_down(sum, off, 64);
                cnt += __shfl_down(cnt, off, 64);
            }
            if (lane == 0) { rs2[wid] = sum; rc2[wid] = cnt; }
            __syncthreads();
            if (tid == 0) {
                float S = 0.0f;
                int G = 0;
                for (int w = 0; w < NW; ++w) { S += rs2[w]; G += (int)rc2[w]; }
                s_neg = S + (float)(k - G) * __uint_as_float(T);
            }
            __syncthreads();
        }
    }

    if (tid == 0) {
        atomicAdd(&acc[0], s_ll);
        atomicAdd(&acc[1], s_lc + s_neg);
        atomicAdd(acc_np, np_b);
        __threadfence();
        unsigned prev = atomicAdd(done, 1u);
        if (prev == BB - 1) {
            int tp = atomicAdd(acc_np, 0);
            float N = (float)max(tp, 1);
            float a0 = atomicAdd(&acc[0], 0.0f);
            float a1 = atomicAdd(&acc[1], 0.0f);
            out[0] = a0 / N;
            out[1] = a1 / N;
        }
    }
}

extern "C" void kernel_launch(void* const* d_in, const int* in_sizes, int n_in,
                              void* d_out, int out_size, void* d_ws, size_t ws_size,
                              hipStream_t stream) {
    const float* loc    = (const float*)d_in[0];
    const float* conf   = (const float*)d_in[1];
    const float* priors = (const float*)d_in[2];
    const float* gt     = (const float*)d_in[3];
    const int*   labels = (const int*)d_in[4];
    float* out = (float*)d_out;

    char* ws = (char*)d_ws;
    const size_t SZ_BP = (size_t)BB * PP * 4;          // 1,231,872 B
    const size_t SZ_SLOT = (size_t)BB * NSLOTW * 4;    // 154,624 B
    // [0,4096) gkey | [4096,4104) acc | [4104,4108) acc_np | [4108,4112) done | pad 4224
    unsigned long long* gkey = (unsigned long long*)ws;
    float*    acc    = (float*)   (ws + 4096);
    int*      acc_np = (int*)     (ws + 4104);
    unsigned* done   = (unsigned*)(ws + 4108);
    unsigned* bp  = (unsigned*)(ws + 4224);
    float* mine = (float*)(ws + 4224 + SZ_BP);
    float* p_ll = (float*)(ws + 4224 + 2 * SZ_BP);
    float* p_lc = (float*)(ws + 4224 + 2 * SZ_BP + SZ_SLOT);
    int*   p_np = (int*)  (ws + 4224 + 2 * SZ_BP + 2 * SZ_SLOT);

    (void)hipMemsetAsync(ws, 0, 4224, stream);   // gkey + acc + acc_np + done

    k_match<<<MBLK, MTB, 0, stream>>>(priors, gt, gkey);

    dim3 pg(NMB, BB);
    k_prior<<<pg, MTB, 0, stream>>>(priors, gt, labels, bp);

    k_force<<<1, 512, 0, stream>>>(labels, gkey, bp);

    dim3 kg(NSLOT, BB);
    k_main<<<kg, MAINB, 0, stream>>>(loc, conf, priors, gt, bp,
                                     mine, p_ll, p_lc, p_np);

    k_select<<<BB, ST, 0, stream>>>(mine, p_ll, p_lc, p_np, acc, acc_np, done, out);
}